// Round 1
// baseline (1094.431 us; speedup 1.0000x reference)
//
#include <hip/hip_runtime.h>
#include <hip/hip_bf16.h>

#define D 512
#define NHEADS 8
#define HDIM 64
#define VOCAB 32000
#define NEGV (-1e9f)

typedef __bf16 bf16x8 __attribute__((ext_vector_type(8)));
typedef float  f32x4  __attribute__((ext_vector_type(4)));

static __device__ inline f32x4 mfma16(bf16x8 a, bf16x8 b, f32x4 c) {
    return __builtin_amdgcn_mfma_f32_16x16x32_bf16(a, b, c, 0, 0, 0);
}

// ---------------- init: zero ea, col2slot=-1, counter=0 ----------------
__global__ void init_kernel(float* __restrict__ ea, long long nEa,
                            int* __restrict__ col2slot, int LEXT,
                            int* __restrict__ counter) {
    long long i = (long long)blockIdx.x * blockDim.x + threadIdx.x;
    long long stride = (long long)gridDim.x * blockDim.x;
    for (long long j = i; j < nEa; j += stride) ea[j] = 0.f;
    for (long long j = i; j < LEXT; j += stride) col2slot[j] = -1;
    if (i == 0) *counter = 0;
}

// ---------------- f32 -> bf16 convert ----------------
__global__ void convert_bf16(const float* __restrict__ in, __bf16* __restrict__ outp, int N) {
    int stride = gridDim.x * blockDim.x;
    for (int i = blockIdx.x * blockDim.x + threadIdx.x; i < N; i += stride)
        outp[i] = (__bf16)in[i];
}

// ---------------- transpose 512x512 + convert ----------------
__global__ void transpose_bf16(const float* __restrict__ in, __bf16* __restrict__ outp) {
    int i = blockIdx.x * blockDim.x + threadIdx.x;  // over D*D, coalesced read
    if (i >= D * D) return;
    int k = i / D, n = i % D;
    outp[n * D + k] = (__bf16)in[i];
}

// ---------------- z = tgt@w_lin + b ; log-sigmoid gates ----------------
__global__ __launch_bounds__(256) void z_kernel(const float* __restrict__ tgt,
        const float* __restrict__ wlin, const float* __restrict__ blin,
        float* __restrict__ lk, float* __restrict__ lc, int T) {
    int wave = threadIdx.x >> 6, l = threadIdx.x & 63;
    int t = blockIdx.x * 4 + wave;
    if (t >= T) return;
    const float* row = tgt + (size_t)t * D;
    float s = 0.f;
#pragma unroll
    for (int j = 0; j < 8; ++j) s += row[l * 8 + j] * wlin[l * 8 + j];
    for (int off = 32; off; off >>= 1) s += __shfl_xor(s, off);
    if (l == 0) {
        float z = s + blin[0];
        float lg = log1pf(__expf(-fabsf(z)));
        lc[t] = fminf(z, 0.f) - lg;    // log_sigmoid(z)
        lk[t] = fminf(-z, 0.f) - lg;   // log_sigmoid(-z)
    }
}

// ---------------- assign compact slots to covered columns ----------------
__global__ void assign_kernel(const int* __restrict__ ids, int S,
                              int* __restrict__ col2slot, int* __restrict__ counter) {
    int s = blockIdx.x * blockDim.x + threadIdx.x;
    if (s >= S) return;
    int v = ids[s];
    if (atomicCAS(&col2slot[v], -1, -2) == -1) {
        int j = atomicAdd(counter, 1);
        atomicExch(&col2slot[v], j);
    }
}

// ---------------- C[M][512] = A[M][512] @ Bt[512][512]^T  (bf16 in/out) ----------------
__global__ __launch_bounds__(256) void gemm_proj(const __bf16* __restrict__ A,
        const __bf16* __restrict__ Bt, __bf16* __restrict__ C) {
    const int l = threadIdx.x & 63;
    const int w = threadIdx.x >> 6;
    const int row = blockIdx.x * 16 + (l & 15);
    const int col = blockIdx.y * 64 + w * 16 + (l & 15);
    const int ko = (l >> 4) * 8;
    f32x4 acc = {0.f, 0.f, 0.f, 0.f};
    const __bf16* ap = A + (size_t)row * D + ko;
    const __bf16* bp = Bt + (size_t)col * D + ko;
#pragma unroll
    for (int k = 0; k < D; k += 32) {
        bf16x8 av = *(const bf16x8*)(ap + k);
        bf16x8 bv = *(const bf16x8*)(bp + k);
        acc = mfma16(av, bv, acc);
    }
    const int r0 = blockIdx.x * 16 + (l >> 4) * 4;
#pragma unroll
    for (int i = 0; i < 4; ++i)
        C[(size_t)(r0 + i) * D + col] = (__bf16)acc[i];
}

// ---------------- attention: per 16-row tile, 4 heads per block, 2-pass ----------------
// grid: (T/16, 2). Adds head-averaged softmax probs into ea[t*S + slot].
__global__ __launch_bounds__(256) void attn_kernel(
        const __bf16* __restrict__ Qb, const __bf16* __restrict__ Kb,
        const int* __restrict__ ids, const int* __restrict__ col2slot,
        float* __restrict__ ea, int S) {
    const int l = threadIdx.x & 63;
    const int w = threadIdx.x >> 6;      // 0..3
    const int t0 = blockIdx.x * 16;
    const int hhalf = blockIdx.y;        // 0 or 1
    const int ko = (l >> 4) * 8;
    const float scale = 0.125f;          // 1/sqrt(64)
    const int nst = S / 16;

    __shared__ float smM[4][16][4];
    __shared__ float smZ[4][16][4];
    __shared__ float sfM[4][16];
    __shared__ float sfRZ[4][16];

    // preload Q fragments for 4 heads x 2 k-steps
    bf16x8 aq[4][2];
    const int trow = t0 + (l & 15);
#pragma unroll
    for (int h = 0; h < 4; ++h) {
        const int hb = (hhalf * 4 + h) * HDIM;
        aq[h][0] = *(const bf16x8*)(Qb + (size_t)trow * D + hb + ko);
        aq[h][1] = *(const bf16x8*)(Qb + (size_t)trow * D + hb + 32 + ko);
    }

    // phase A: softmax stats (max, sumexp) per (head, t-row)
#pragma unroll
    for (int h = 0; h < 4; ++h) {
        const int hb = (hhalf * 4 + h) * HDIM;
        float m[4], Z[4];
#pragma unroll
        for (int i = 0; i < 4; ++i) { m[i] = -1e30f; Z[i] = 0.f; }
        for (int st = w; st < nst; st += 4) {
            const int srow = st * 16 + (l & 15);
            bf16x8 b0 = *(const bf16x8*)(Kb + (size_t)srow * D + hb + ko);
            bf16x8 b1 = *(const bf16x8*)(Kb + (size_t)srow * D + hb + 32 + ko);
            f32x4 acc = {0.f, 0.f, 0.f, 0.f};
            acc = mfma16(aq[h][0], b0, acc);
            acc = mfma16(aq[h][1], b1, acc);
#pragma unroll
            for (int i = 0; i < 4; ++i) {
                float sc = acc[i] * scale;
                float nm = fmaxf(m[i], sc);
                Z[i] = Z[i] * __expf(m[i] - nm) + __expf(sc - nm);
                m[i] = nm;
            }
        }
#pragma unroll
        for (int i = 0; i < 4; ++i) {
#pragma unroll
            for (int mask = 1; mask <= 8; mask <<= 1) {
                float om = __shfl_xor(m[i], mask);
                float oZ = __shfl_xor(Z[i], mask);
                float nm = fmaxf(m[i], om);
                Z[i] = Z[i] * __expf(m[i] - nm) + oZ * __expf(om - nm);
                m[i] = nm;
            }
        }
        if ((l & 15) == 0) {
#pragma unroll
            for (int i = 0; i < 4; ++i) {
                int t = (l >> 4) * 4 + i;
                smM[h][t][w] = m[i];
                smZ[h][t][w] = Z[i];
            }
        }
    }
    __syncthreads();
    if (threadIdx.x < 64) {
        int h = threadIdx.x >> 4, t = threadIdx.x & 15;
        float m = smM[h][t][0], Z = smZ[h][t][0];
#pragma unroll
        for (int w2 = 1; w2 < 4; ++w2) {
            float om = smM[h][t][w2], oZ = smZ[h][t][w2];
            float nm = fmaxf(m, om);
            Z = Z * __expf(m - nm) + oZ * __expf(om - nm);
            m = nm;
        }
        sfM[h][t] = m;
        sfRZ[h][t] = 1.f / Z;
    }
    __syncthreads();

    float mF[4][4], rZ[4][4];
#pragma unroll
    for (int h = 0; h < 4; ++h)
#pragma unroll
        for (int i = 0; i < 4; ++i) {
            int t = (l >> 4) * 4 + i;
            mF[h][i] = sfM[h][t];
            rZ[h][i] = sfRZ[h][t];
        }

    // phase B: recompute scores, head-sum probabilities, scatter into ea
    for (int st = w; st < nst; st += 4) {
        const int s = st * 16 + (l & 15);
        float psum[4] = {0.f, 0.f, 0.f, 0.f};
#pragma unroll
        for (int h = 0; h < 4; ++h) {
            const int hb = (hhalf * 4 + h) * HDIM;
            bf16x8 b0 = *(const bf16x8*)(Kb + (size_t)s * D + hb + ko);
            bf16x8 b1 = *(const bf16x8*)(Kb + (size_t)s * D + hb + 32 + ko);
            f32x4 acc = {0.f, 0.f, 0.f, 0.f};
            acc = mfma16(aq[h][0], b0, acc);
            acc = mfma16(aq[h][1], b1, acc);
#pragma unroll
            for (int i = 0; i < 4; ++i) {
                float sc = acc[i] * scale;
                psum[i] += __expf(sc - mF[h][i]) * rZ[h][i];
            }
        }
        int slot = col2slot[ids[s]];
#pragma unroll
        for (int i = 0; i < 4; ++i) {
            int t = t0 + (l >> 4) * 4 + i;
            atomicAdd(&ea[(size_t)t * S + slot], psum[i] * 0.125f);
        }
    }
}

// ---------------- final: fused log_softmax + gather + logaddexp ----------------
__global__ __launch_bounds__(256) void final_kernel(
        const float* __restrict__ logits, const float* __restrict__ lk,
        const float* __restrict__ lc, const int* __restrict__ col2slot,
        const float* __restrict__ ea, float* __restrict__ outp,
        int S, int LEXT) {
    const int t = blockIdx.x;
    const int tid = threadIdx.x;
    __shared__ float red[8];
    const float* lrow = logits + (size_t)t * VOCAB;

    // pass 1: row max
    float mx = -1e30f;
    for (int i = tid; i < VOCAB / 4; i += 256) {
        float4 v = ((const float4*)lrow)[i];
        mx = fmaxf(mx, fmaxf(fmaxf(v.x, v.y), fmaxf(v.z, v.w)));
    }
    for (int off = 32; off; off >>= 1) mx = fmaxf(mx, __shfl_xor(mx, off));
    if ((tid & 63) == 0) red[tid >> 6] = mx;
    __syncthreads();
    mx = fmaxf(fmaxf(red[0], red[1]), fmaxf(red[2], red[3]));

    // pass 2: sumexp
    float Zs = 0.f;
    for (int i = tid; i < VOCAB / 4; i += 256) {
        float4 v = ((const float4*)lrow)[i];
        Zs += __expf(v.x - mx) + __expf(v.y - mx) + __expf(v.z - mx) + __expf(v.w - mx);
    }
    for (int off = 32; off; off >>= 1) Zs += __shfl_xor(Zs, off);
    if ((tid & 63) == 0) red[4 + (tid >> 6)] = Zs;
    __syncthreads();
    const float lse = mx + __logf(red[4] + red[5] + red[6] + red[7]);

    const float lkt = lk[t], lct = lc[t];
    float* orow = outp + (size_t)t * LEXT;
    const float* earow = ea + (size_t)t * S;
    for (int v = tid; v < LEXT; v += 256) {
        int slot = col2slot[v];
        float dec = (v < VOCAB) ? (lrow[v] - lse) : NEGV;
        float ptr = NEGV;
        if (slot >= 0) {
            float e = earow[slot];
            if (e > 0.f) ptr = __logf(e);
        }
        float a = dec + lkt;
        float b = ptr + lct;
        float hi = fmaxf(a, b), lo = fminf(a, b);
        orow[v] = hi + log1pf(__expf(lo - hi));
    }
}

extern "C" void kernel_launch(void* const* d_in, const int* in_sizes, int n_in,
                              void* d_out, int out_size, void* d_ws, size_t ws_size,
                              hipStream_t stream) {
    const float* logits = (const float*)d_in[0];
    const int*   ids    = (const int*)d_in[1];
    const float* src    = (const float*)d_in[2];
    const float* tgt    = (const float*)d_in[3];
    // d_in[4] = len_extended_vocab (device scalar) — derived from out_size instead
    const float* wlin   = (const float*)d_in[5];
    const float* blin   = (const float*)d_in[6];
    const float* Wq     = (const float*)d_in[7];
    const float* Wk     = (const float*)d_in[8];
    float* outp = (float*)d_out;

    const int S    = in_sizes[1];
    const int T    = in_sizes[3] / D;
    const int LEXT = out_size / T;

    char* ws = (char*)d_ws;
    size_t off = 0;
    auto alloc = [&](size_t bytes) -> void* {
        void* p = ws + off;
        off += (bytes + 255) & ~(size_t)255;
        return p;
    };
    float*  lk       = (float*)alloc((size_t)T * 4);
    float*  lc       = (float*)alloc((size_t)T * 4);
    int*    col2slot = (int*)alloc((size_t)LEXT * 4);
    int*    counter  = (int*)alloc(256);
    __bf16* tgt_bf   = (__bf16*)alloc((size_t)T * D * 2);
    __bf16* src_bf   = (__bf16*)alloc((size_t)S * D * 2);
    __bf16* WqT      = (__bf16*)alloc((size_t)D * D * 2);
    __bf16* WkT      = (__bf16*)alloc((size_t)D * D * 2);
    __bf16* Qb       = (__bf16*)alloc((size_t)T * D * 2);
    __bf16* Kb       = (__bf16*)alloc((size_t)S * D * 2);
    float*  ea       = (float*)alloc((size_t)T * S * 4);

    init_kernel<<<2048, 256, 0, stream>>>(ea, (long long)T * S, col2slot, LEXT, counter);
    convert_bf16<<<1024, 256, 0, stream>>>(tgt, tgt_bf, T * D);
    convert_bf16<<<1024, 256, 0, stream>>>(src, src_bf, S * D);
    transpose_bf16<<<(D * D + 255) / 256, 256, 0, stream>>>(Wq, WqT);
    transpose_bf16<<<(D * D + 255) / 256, 256, 0, stream>>>(Wk, WkT);
    z_kernel<<<T / 4, 256, 0, stream>>>(tgt, wlin, blin, lk, lc, T);
    assign_kernel<<<(S + 255) / 256, 256, 0, stream>>>(ids, S, col2slot, counter);
    gemm_proj<<<dim3(T / 16, D / 64), 256, 0, stream>>>(tgt_bf, WqT, Qb);
    gemm_proj<<<dim3(S / 16, D / 64), 256, 0, stream>>>(src_bf, WkT, Kb);
    attn_kernel<<<dim3(T / 16, 2), 256, 0, stream>>>(Qb, Kb, ids, col2slot, ea, S);
    final_kernel<<<T, 256, 0, stream>>>(logits, lk, lc, col2slot, ea, outp, S, LEXT);
}